// Round 3
// baseline (5150.418 us; speedup 1.0000x reference)
//
#include <hip/hip_runtime.h>
#include <hip/hip_bf16.h>

typedef __bf16 bf16_t;
typedef bf16_t bf16x8 __attribute__((ext_vector_type(8)));
typedef float f32x4 __attribute__((ext_vector_type(4)));
typedef unsigned long long u64;

#define T_SEQ 512
#define NB 128
#define HID 1024
#define FIN 64
#define HB (NB * HID)            // 131072 elems = 256 KB per h snapshot
#define NBLK 256                 // 64 L0 + 64 X1 + 128 L1  (all 256 CUs)
#define DM 32                    // master h ring depth
#define DX 8                     // X1 partial ring depth
#define X1SLOT (4096 * NB)       // floats per X1 slot

// Fragment-contiguous weight LDS (R2): frag*1024B + lane*16B, conflict-free.
#define NF0 136                  // L0 frags: 34 k-chunks x 4 row-tiles
#define NF1 128                  // X1 frags: 32 x 4
#define NFR 64                   // L1 frags: 32 x 2
#define L0_STAGE (NF0 * 64 * 8)  // elems: 69632
#define L1_STAGE (NFR * 64 * 8)  // elems: 32768
// L0 LDS: weights 139264B + stage 4096B + c_lds 8192B = 151552B
#define LDS_BYTES 151552

#define F0 0      // f0[64]:  L0 block flags
#define FX 64     // fX[64]:  X1 block flags
#define F1 128    // f1[128]: L1 block flags
#define SYNC_N 256

__device__ __forceinline__ float sigm_f(float x) { return 1.0f / (1.0f + __expf(-x)); }
__device__ __forceinline__ float tanh_f(float x) { return 2.0f * sigm_f(2.0f * x) - 1.0f; }

__device__ __forceinline__ unsigned ldcnt(const unsigned* p) {
    return __hip_atomic_load(p, __ATOMIC_RELAXED, __HIP_MEMORY_SCOPE_AGENT);
}
__device__ __forceinline__ void stw32(unsigned* p, unsigned v) {
    __hip_atomic_store(p, v, __ATOMIC_RELAXED, __HIP_MEMORY_SCOPE_AGENT);
}
__device__ __forceinline__ void stwf(float* p, float v) {
    __hip_atomic_store(p, v, __ATOMIC_RELAXED, __HIP_MEMORY_SCOPE_AGENT);
}
__device__ __forceinline__ void stw64(u64* p, u64 v) {
    __hip_atomic_store(p, v, __ATOMIC_RELAXED, __HIP_MEMORY_SCOPE_AGENT);
}

// Readiness prefix over pair-gated panels: panel p ready iff flags[2p],[2p+1] >= thr.
__device__ __forceinline__ int prefix_pairs(const unsigned* f, unsigned thr) {
    unsigned v = ldcnt(&f[threadIdx.x & 63]);
    u64 b = __ballot(v >= thr);
    b &= (b >> 1);
    u64 nr = ~b & 0x5555555555555555ull;
    if (nr == 0) return 32;
    return (__ffsll(nr) - 1) >> 1;
}
// Quad-gated (L1): panel p ready iff flags[4p..4p+3] >= thr (128 flags).
__device__ __forceinline__ int prefix_quads(const unsigned* f, unsigned thr) {
    const int ln = threadIdx.x & 63;
    unsigned v0 = ldcnt(&f[ln]);
    unsigned v1 = ldcnt(&f[64 + ln]);
    u64 b0 = __ballot(v0 >= thr);
    u64 b1 = __ballot(v1 >= thr);
    u64 q0 = b0 & (b0 >> 1) & (b0 >> 2) & (b0 >> 3);
    u64 q1 = b1 & (b1 >> 1) & (b1 >> 2) & (b1 >> 3);
    u64 nr0 = ~q0 & 0x1111111111111111ull;
    if (nr0) return (__ffsll(nr0) - 1) >> 2;
    u64 nr1 = ~q1 & 0x1111111111111111ull;
    if (nr1) return 16 + ((__ffsll(nr1) - 1) >> 2);
    return 32;
}

__global__ __launch_bounds__(256) void prep_kernel(
    const float* __restrict__ x,
    const float* __restrict__ Wih0, const float* __restrict__ Whh0,
    const float* __restrict__ bih0, const float* __restrict__ bhh0,
    const float* __restrict__ Wih1, const float* __restrict__ Whh1,
    const float* __restrict__ bih1, const float* __restrict__ bhh1,
    const float* __restrict__ Wfc,
    bf16_t* __restrict__ Wf0, bf16_t* __restrict__ Wf1, bf16_t* __restrict__ WfR,
    bf16_t* __restrict__ xswz, bf16_t* __restrict__ Wfcb,
    float* __restrict__ bias0, float* __restrict__ bias1,
    bf16_t* __restrict__ mh0, bf16_t* __restrict__ mh1,
    unsigned* __restrict__ sync)
{
    const unsigned stride = gridDim.x * blockDim.x;
    const unsigned i0 = blockIdx.x * blockDim.x + threadIdx.x;

    for (unsigned i = i0; i < SYNC_N; i += stride) sync[i] = 0u;

    for (unsigned i = i0; i < 64u * NF0 * 64u; i += stride) {
        unsigned g0 = i / (NF0 * 64u), rem = i % (NF0 * 64u);
        unsigned f = rem >> 6, ln = rem & 63u;
        unsigned pc = f >> 2, mt = f & 3u;
        unsigned r = mt * 16u + (ln & 15u);
        unsigned row = (r & 3u) * HID + g0 * 16u + (r >> 2);
        unsigned k0 = pc * 32u + (ln >> 4) * 8u;
        bf16_t* dst = Wf0 + (size_t)i * 8;
#pragma unroll
        for (int e = 0; e < 8; ++e) {
            unsigned k = k0 + e;
            float v = (k < FIN) ? Wih0[(size_t)row * FIN + k]
                                : Whh0[(size_t)row * HID + (k - FIN)];
            dst[e] = (bf16_t)v;
        }
    }
    for (unsigned i = i0; i < 64u * NF1 * 64u; i += stride) {
        unsigned g = i >> 13, rem = i & 8191u;
        unsigned f = rem >> 6, ln = rem & 63u;
        unsigned pc = f >> 2, mt = f & 3u;
        unsigned r = mt * 16u + (ln & 15u);
        unsigned row = (r & 3u) * HID + g * 16u + (r >> 2);
        unsigned k0 = pc * 32u + (ln >> 4) * 8u;
        bf16_t* dst = Wf1 + (size_t)i * 8;
#pragma unroll
        for (int e = 0; e < 8; ++e)
            dst[e] = (bf16_t)Wih1[(size_t)row * HID + k0 + e];
    }
    for (unsigned i = i0; i < 128u * NFR * 64u; i += stride) {
        unsigned g1 = i >> 12, rem = i & 4095u;
        unsigned f = rem >> 6, ln = rem & 63u;
        unsigned pc = f >> 1, mt = f & 1u;
        unsigned r = mt * 16u + (ln & 15u);
        unsigned row = (r & 3u) * HID + g1 * 8u + (r >> 2);
        unsigned k0 = pc * 32u + (ln >> 4) * 8u;
        bf16_t* dst = WfR + (size_t)i * 8;
#pragma unroll
        for (int e = 0; e < 8; ++e)
            dst[e] = (bf16_t)Whh1[(size_t)row * HID + k0 + e];
    }
    for (unsigned i = i0; i < 4194304u; i += stride) {
        unsigned e = i & 7u, unit = i >> 3;
        unsigned lane = unit & 63u, g = unit >> 6;
        unsigned wvv = g & 7u, pt = g >> 3;
        unsigned p = pt & 1u, t = pt >> 1;
        unsigned n = wvv * 16u + (lane & 15u);
        unsigned k = p * 32u + (lane >> 4) * 8u + e;
        xswz[i] = (bf16_t)x[((size_t)n * T_SEQ + t) * FIN + k];
    }
    for (unsigned i = i0; i < 64u * HID; i += stride)
        Wfcb[i] = (bf16_t)Wfc[i];
    for (unsigned i = i0; i < (unsigned)(DM * HB); i += stride) {
        mh0[i] = (bf16_t)0.0f; mh1[i] = (bf16_t)0.0f;
    }
    for (unsigned i = i0; i < 4096u; i += stride) {
        bias0[i] = bih0[i] + bhh0[i];
        bias1[i] = bih1[i] + bhh1[i];
    }
}

// Persistent cooperative kernel, 256 blocks x 512 threads, 1 block/CU.
// Dataflow: panel-granular consumption. Panel p of a 256KB h snapshot is gated
// on only its own producers' flags (pairs for 16-unit producers, quads for
// 8-unit producers), so consumers track producers with ~1-panel lag instead of
// waiting for the max over all 64/128 blocks each step.
__global__ __launch_bounds__(512) void lstm_persist(
    const bf16_t* __restrict__ Wf0, const bf16_t* __restrict__ Wf1,
    const bf16_t* __restrict__ WfR,
    const float* __restrict__ bias0, const float* __restrict__ bias1,
    const bf16_t* __restrict__ xswz,
    bf16_t* __restrict__ mh0, bf16_t* __restrict__ mh1,
    bf16_t* __restrict__ h2buf,
    float* __restrict__ x1r,
    unsigned* __restrict__ sync)
{
    extern __shared__ bf16_t Wl[];
    const int b = blockIdx.x;
    const int tid = threadIdx.x;
    const int wv = tid >> 6;
    const int lane = tid & 63;
    const int q = lane >> 4;
    const int l = lane & 15;
    const int nn = wv * 16 + l;

    if (b < 64) {
        // ================= L0: layer-0 recurrence =================
        const int g0 = b;
        for (int c = tid; c < NF0 * 64; c += 512)
            *(bf16x8*)(Wl + (size_t)c * 8) =
                *(const bf16x8*)(Wf0 + ((size_t)g0 * (NF0 * 64) + c) * 8);
        bf16_t* stage = Wl + L0_STAGE;
        float* cl = (float*)(Wl + L0_STAGE + 2048);      // [16][NB] cell state
        for (int i = tid; i < 16 * NB; i += 512) cl[i] = 0.0f;
        float bj[4][4];
#pragma unroll
        for (int mt = 0; mt < 4; ++mt) {
            const int j = g0 * 16 + mt * 4 + q;
#pragma unroll
            for (int gg = 0; gg < 4; ++gg) bj[mt][gg] = bias0[gg * HID + j];
        }
        __syncthreads();

        for (int t = 0; t < T_SEQ; ++t) {
            if (t >= DM) {       // mh0 slot-overwrite guard (X1 must have read t-32)
                const unsigned tB = (unsigned)(t - (DM - 1));
                while (!__all(ldcnt(&sync[FX + lane]) >= tB)) __builtin_amdgcn_s_sleep(8);
            }
            f32x4 acc[4] = {{0.f,0.f,0.f,0.f},{0.f,0.f,0.f,0.f},{0.f,0.f,0.f,0.f},{0.f,0.f,0.f,0.f}};
            {   // x panels: no dependency
                const bf16_t* X = xswz + (size_t)t * 8192;
#pragma unroll
                for (int p = 0; p < 2; ++p) {
                    bf16x8 bv = *(const bf16x8*)(X + (((size_t)p * 8 + wv) * 64 + lane) * 8);
#pragma unroll
                    for (int mt = 0; mt < 4; ++mt) {
                        bf16x8 av = *(const bf16x8*)(Wl + ((size_t)(p * 4 + mt) * 64 + lane) * 8);
                        acc[mt] = __builtin_amdgcn_mfma_f32_16x16x32_bf16(av, bv, acc[mt], 0, 0, 0);
                    }
                }
            }
            // h panels from mh0[t-1], pair-gated per panel
            const bf16_t* B = mh0 + (size_t)((t + DM - 1) & (DM - 1)) * HB;
            const unsigned thr = (unsigned)t;
            int R = prefix_pairs(sync + F0, thr);
            bf16x8 bb[16];
            while (R < 8)  { __builtin_amdgcn_s_sleep(2); R = prefix_pairs(sync + F0, thr); }
            __asm__ volatile("" ::: "memory");
#pragma unroll
            for (int i = 0; i < 8; ++i)
                bb[i] = *(const bf16x8*)(B + (((size_t)i * 8 + wv) * 64 + lane) * 8);
            while (R < 16) { __builtin_amdgcn_s_sleep(2); R = prefix_pairs(sync + F0, thr); }
            __asm__ volatile("" ::: "memory");
#pragma unroll
            for (int i = 8; i < 16; ++i)
                bb[i] = *(const bf16x8*)(B + (((size_t)i * 8 + wv) * 64 + lane) * 8);
#pragma unroll
            for (int gq = 0; gq < 4; ++gq) {
#pragma unroll
                for (int pp = 0; pp < 8; ++pp) {
                    const int p = gq * 8 + pp;
                    bf16x8 bv = bb[(gq & 1) * 8 + pp];
#pragma unroll
                    for (int mt = 0; mt < 4; ++mt) {
                        bf16x8 av = *(const bf16x8*)(Wl + ((size_t)((2 + p) * 4 + mt) * 64 + lane) * 8);
                        acc[mt] = __builtin_amdgcn_mfma_f32_16x16x32_bf16(av, bv, acc[mt], 0, 0, 0);
                    }
                }
                if (gq < 2) {
                    const int np0 = 16 + gq * 8;
                    while (R < np0 + 8) { __builtin_amdgcn_s_sleep(2); R = prefix_pairs(sync + F0, thr); }
                    __asm__ volatile("" ::: "memory");
#pragma unroll
                    for (int i = 0; i < 8; ++i)
                        bb[(gq & 1) * 8 + i] =
                            *(const bf16x8*)(B + (((size_t)(np0 + i) * 8 + wv) * 64 + lane) * 8);
                }
            }
            // cell update (c in LDS, lane-private rows) -> stage
#pragma unroll
            for (int mt = 0; mt < 4; ++mt) {
                const int u = mt * 4 + q;
                float iv = sigm_f(acc[mt][0] + bj[mt][0]);
                float fv = sigm_f(acc[mt][1] + bj[mt][1]);
                float gv = tanh_f(acc[mt][2] + bj[mt][2]);
                float ov = sigm_f(acc[mt][3] + bj[mt][3]);
                float cn = fv * cl[u * NB + nn] + iv * gv;
                cl[u * NB + nn] = cn;
                stage[nn * 16 + u] = (bf16_t)(ov * tanh_f(cn));
            }
            // per-wave master write (stage rows wv*16.. are same-wave-owned)
            {
                u64 v = *(const u64*)(stage + (size_t)(wv * 16 + l) * 16 + (q >> 1) * 8 + (q & 1) * 4);
                size_t unit = ((size_t)(g0 >> 1) * 8 + wv) * 64 + ((size_t)(g0 & 1) * 2 + (q >> 1)) * 16 + l;
                stw64((u64*)(mh0 + (size_t)(t & (DM - 1)) * HB) + unit * 2 + (q & 1), v);
            }
            __syncthreads();   // drains all waves' stores (vmcnt 0 at barrier)
            if (tid == 0) stw32(&sync[F0 + g0], (unsigned)(t + 1));
        }
    } else if (b < 128) {
        // ================= X1: W_ih1 @ h0[t] partials =================
        const int g = b - 64;
        for (int c = tid; c < NF1 * 64; c += 512)
            *(bf16x8*)(Wl + (size_t)c * 8) =
                *(const bf16x8*)(Wf1 + ((size_t)g * (NF1 * 64) + c) * 8);
        __syncthreads();

        for (int t = 0; t < T_SEQ; ++t) {
            if (t >= DX) {       // x1r slot-overwrite guard
                const unsigned tC = (unsigned)(t - (DX - 1));
                while (!(__all(ldcnt(&sync[F1 + lane]) >= tC)
                      && __all(ldcnt(&sync[F1 + 64 + lane]) >= tC)))
                    __builtin_amdgcn_s_sleep(8);
            }
            f32x4 acc[4] = {{0.f,0.f,0.f,0.f},{0.f,0.f,0.f,0.f},{0.f,0.f,0.f,0.f},{0.f,0.f,0.f,0.f}};
            const bf16_t* B = mh0 + (size_t)(t & (DM - 1)) * HB;
            const unsigned thr = (unsigned)(t + 1);
            int R = prefix_pairs(sync + F0, thr);
            bf16x8 bb[16];
            while (R < 8)  { __builtin_amdgcn_s_sleep(2); R = prefix_pairs(sync + F0, thr); }
            __asm__ volatile("" ::: "memory");
#pragma unroll
            for (int i = 0; i < 8; ++i)
                bb[i] = *(const bf16x8*)(B + (((size_t)i * 8 + wv) * 64 + lane) * 8);
            while (R < 16) { __builtin_amdgcn_s_sleep(2); R = prefix_pairs(sync + F0, thr); }
            __asm__ volatile("" ::: "memory");
#pragma unroll
            for (int i = 8; i < 16; ++i)
                bb[i] = *(const bf16x8*)(B + (((size_t)i * 8 + wv) * 64 + lane) * 8);
#pragma unroll
            for (int gq = 0; gq < 4; ++gq) {
#pragma unroll
                for (int pp = 0; pp < 8; ++pp) {
                    const int p = gq * 8 + pp;
                    bf16x8 bv = bb[(gq & 1) * 8 + pp];
#pragma unroll
                    for (int mt = 0; mt < 4; ++mt) {
                        bf16x8 av = *(const bf16x8*)(Wl + ((size_t)(p * 4 + mt) * 64 + lane) * 8);
                        acc[mt] = __builtin_amdgcn_mfma_f32_16x16x32_bf16(av, bv, acc[mt], 0, 0, 0);
                    }
                }
                if (gq < 2) {
                    const int np0 = 16 + gq * 8;
                    while (R < np0 + 8) { __builtin_amdgcn_s_sleep(2); R = prefix_pairs(sync + F0, thr); }
                    __asm__ volatile("" ::: "memory");
#pragma unroll
                    for (int i = 0; i < 8; ++i)
                        bb[(gq & 1) * 8 + i] =
                            *(const bf16x8*)(B + (((size_t)(np0 + i) * 8 + wv) * 64 + lane) * 8);
                }
            }
            {   // scatter partials (write-through f32)
                float* P = x1r + (size_t)(t & (DX - 1)) * X1SLOT + (size_t)g * 64 * NB;
#pragma unroll
                for (int mt = 0; mt < 4; ++mt)
#pragma unroll
                    for (int jj = 0; jj < 4; ++jj)
                        stwf(P + (size_t)((mt * 4 + q) * 4 + jj) * NB + nn, acc[mt][jj]);
            }
            __syncthreads();
            if (tid == 0) stw32(&sync[FX + g], (unsigned)(t + 1));
        }
    } else {
        // ================= L1: layer-1 recurrent half =================
        const int g1 = b - 128;
        for (int c = tid; c < NFR * 64; c += 512)
            *(bf16x8*)(Wl + (size_t)c * 8) =
                *(const bf16x8*)(WfR + ((size_t)g1 * (NFR * 64) + c) * 8);
        bf16_t* stage = Wl + L1_STAGE;
        float* cl = (float*)(Wl + L1_STAGE + 1024);      // [8][NB]
        for (int i = tid; i < 8 * NB; i += 512) cl[i] = 0.0f;
        float bj[2][4];
#pragma unroll
        for (int mt = 0; mt < 2; ++mt) {
            const int j = g1 * 8 + mt * 4 + q;
#pragma unroll
            for (int gg = 0; gg < 4; ++gg) bj[mt][gg] = bias1[gg * HID + j];
        }
        __syncthreads();

        for (int t = 0; t < T_SEQ; ++t) {
            // fX gate (single flag) + EARLY partial loads (latency hidden by panel loop)
            {
                const unsigned tA = (unsigned)(t + 1);
                while (!__all(ldcnt(&sync[FX + (g1 >> 1)]) >= tA)) __builtin_amdgcn_s_sleep(2);
                __asm__ volatile("" ::: "memory");
            }
            float pv[2][4];
            {
                const float* P = x1r + (size_t)(t & (DX - 1)) * X1SLOT + (size_t)g1 * 32 * NB;
#pragma unroll
                for (int mt = 0; mt < 2; ++mt)
#pragma unroll
                    for (int jj = 0; jj < 4; ++jj)
                        pv[mt][jj] = P[(size_t)((mt * 4 + q) * 4 + jj) * NB + nn];
            }
            f32x4 acc[2] = {{0.f,0.f,0.f,0.f},{0.f,0.f,0.f,0.f}};
            // h1[t-1] panels, quad-gated per panel
            const bf16_t* B1 = mh1 + (size_t)((t + DM - 1) & (DM - 1)) * HB;
            const unsigned thr = (unsigned)t;
            int R = prefix_quads(sync + F1, thr);
            bf16x8 bb[16];
            while (R < 8)  { __builtin_amdgcn_s_sleep(2); R = prefix_quads(sync + F1, thr); }
            __asm__ volatile("" ::: "memory");
#pragma unroll
            for (int i = 0; i < 8; ++i)
                bb[i] = *(const bf16x8*)(B1 + (((size_t)i * 8 + wv) * 64 + lane) * 8);
            while (R < 16) { __builtin_amdgcn_s_sleep(2); R = prefix_quads(sync + F1, thr); }
            __asm__ volatile("" ::: "memory");
#pragma unroll
            for (int i = 8; i < 16; ++i)
                bb[i] = *(const bf16x8*)(B1 + (((size_t)i * 8 + wv) * 64 + lane) * 8);
#pragma unroll
            for (int gq = 0; gq < 4; ++gq) {
#pragma unroll
                for (int pp = 0; pp < 8; ++pp) {
                    const int p = gq * 8 + pp;
                    bf16x8 bv = bb[(gq & 1) * 8 + pp];
#pragma unroll
                    for (int mt = 0; mt < 2; ++mt) {
                        bf16x8 av = *(const bf16x8*)(Wl + ((size_t)(p * 2 + mt) * 64 + lane) * 8);
                        acc[mt] = __builtin_amdgcn_mfma_f32_16x16x32_bf16(av, bv, acc[mt], 0, 0, 0);
                    }
                }
                if (gq < 2) {
                    const int np0 = 16 + gq * 8;
                    while (R < np0 + 8) { __builtin_amdgcn_s_sleep(2); R = prefix_quads(sync + F1, thr); }
                    __asm__ volatile("" ::: "memory");
#pragma unroll
                    for (int i = 0; i < 8; ++i)
                        bb[(gq & 1) * 8 + i] =
                            *(const bf16x8*)(B1 + (((size_t)(np0 + i) * 8 + wv) * 64 + lane) * 8);
                }
            }
#pragma unroll
            for (int mt = 0; mt < 2; ++mt) {
                const int u = mt * 4 + q;
                float iv = sigm_f(acc[mt][0] + pv[mt][0] + bj[mt][0]);
                float fv = sigm_f(acc[mt][1] + pv[mt][1] + bj[mt][1]);
                float gv = tanh_f(acc[mt][2] + pv[mt][2] + bj[mt][2]);
                float ov = sigm_f(acc[mt][3] + pv[mt][3] + bj[mt][3]);
                float cn = fv * cl[u * NB + nn] + iv * gv;
                cl[u * NB + nn] = cn;
                stage[nn * 8 + u] = (bf16_t)(ov * tanh_f(cn));
            }
            u64 v = 0;
            if (q < 2) {   // per-wave master write (32 lanes)
                v = *(const u64*)(stage + (size_t)(wv * 16 + l) * 8 + q * 4);
                size_t unit = ((size_t)(g1 >> 2) * 8 + wv) * 64 + (size_t)(g1 & 3) * 16 + l;
                stw64((u64*)(mh1 + (size_t)(t & (DM - 1)) * HB) + unit * 2 + q, v);
            }
            __syncthreads();
            if (tid == 0) stw32(&sync[F1 + g1], (unsigned)(t + 1));
            if (q < 2)     // h2 history after flag (off the chain)
                *(u64*)(h2buf + ((size_t)(wv * 16 + l) * T_SEQ + t) * HID + g1 * 8 + q * 4) = v;
        }
    }
}

__global__ __launch_bounds__(256) void fc_kernel(
    const bf16_t* __restrict__ h2buf, const bf16_t* __restrict__ Wfcb,
    const float* __restrict__ bfc, float* __restrict__ out)
{
    const int tid = threadIdx.x, wv = tid >> 6, lane = tid & 63;
    const int q = lane >> 4, l = lane & 15;
    const int m0 = blockIdx.x * 64 + wv * 16;
    const bf16_t* arow = h2buf + (size_t)(m0 + l) * HID + q * 8;
    const bf16_t* brow = Wfcb + (size_t)l * HID + q * 8;
    f32x4 acc[4] = {{0.f,0.f,0.f,0.f},{0.f,0.f,0.f,0.f},{0.f,0.f,0.f,0.f},{0.f,0.f,0.f,0.f}};
#pragma unroll 4
    for (int p = 0; p < 32; ++p) {
        bf16x8 av = *(const bf16x8*)(arow + p * 32);
#pragma unroll
        for (int ntile = 0; ntile < 4; ++ntile) {
            bf16x8 bv = *(const bf16x8*)(brow + (size_t)ntile * 16 * HID + p * 32);
            acc[ntile] = __builtin_amdgcn_mfma_f32_16x16x32_bf16(av, bv, acc[ntile], 0, 0, 0);
        }
    }
#pragma unroll
    for (int ntile = 0; ntile < 4; ++ntile) {
        float bv = bfc[ntile * 16 + l];
#pragma unroll
        for (int r = 0; r < 4; ++r)
            out[(size_t)(m0 + q * 4 + r) * 64 + ntile * 16 + l] = acc[ntile][r] + bv;
    }
}

extern "C" void kernel_launch(void* const* d_in, const int* in_sizes, int n_in,
                              void* d_out, int out_size, void* d_ws, size_t ws_size,
                              hipStream_t stream)
{
    const float* x    = (const float*)d_in[0];
    const float* Wih0 = (const float*)d_in[1];
    const float* Whh0 = (const float*)d_in[2];
    const float* bih0 = (const float*)d_in[3];
    const float* bhh0 = (const float*)d_in[4];
    const float* Wih1 = (const float*)d_in[5];
    const float* Whh1 = (const float*)d_in[6];
    const float* bih1 = (const float*)d_in[7];
    const float* bhh1 = (const float*)d_in[8];
    const float* Wfc  = (const float*)d_in[9];
    const float* bfc  = (const float*)d_in[10];
    float* out = (float*)d_out;

    char* ws = (char*)d_ws;
    size_t off = 0;
    auto alloc = [&](size_t bytes) -> void* {
        void* p = ws + off;
        off += (bytes + 255) & ~(size_t)255;
        return p;
    };
    bf16_t* Wf0  = (bf16_t*)alloc((size_t)64 * NF0 * 64 * 8 * 2);
    bf16_t* Wf1  = (bf16_t*)alloc((size_t)64 * NF1 * 64 * 8 * 2);
    bf16_t* WfR  = (bf16_t*)alloc((size_t)128 * NFR * 64 * 8 * 2);
    bf16_t* xswz = (bf16_t*)alloc((size_t)NB * T_SEQ * FIN * 2);
    bf16_t* h2buf= (bf16_t*)alloc((size_t)NB * T_SEQ * HID * 2);
    bf16_t* mh0  = (bf16_t*)alloc((size_t)DM * HB * 2);
    bf16_t* mh1  = (bf16_t*)alloc((size_t)DM * HB * 2);
    float*  x1r  = (float*)alloc((size_t)DX * X1SLOT * 4);
    float*  bias0= (float*)alloc(4096 * 4);
    float*  bias1= (float*)alloc(4096 * 4);
    bf16_t* Wfcb = (bf16_t*)alloc((size_t)64 * HID * 2);
    unsigned* syncp = (unsigned*)alloc(SYNC_N * 4);
    if (off > ws_size) return;

    hipFuncSetAttribute((const void*)lstm_persist,
                        hipFuncAttributeMaxDynamicSharedMemorySize, LDS_BYTES);

    prep_kernel<<<1024, 256, 0, stream>>>(x, Wih0, Whh0, bih0, bhh0,
                                          Wih1, Whh1, bih1, bhh1, Wfc,
                                          Wf0, Wf1, WfR, xswz, Wfcb,
                                          bias0, bias1, mh0, mh1, syncp);

    void* args[] = { (void*)&Wf0, (void*)&Wf1, (void*)&WfR,
                     (void*)&bias0, (void*)&bias1,
                     (void*)&xswz, (void*)&mh0, (void*)&mh1,
                     (void*)&h2buf, (void*)&x1r,
                     (void*)&syncp };
    hipLaunchCooperativeKernel((void*)lstm_persist, dim3(NBLK), dim3(512),
                               args, LDS_BYTES, stream);

    fc_kernel<<<(NB * T_SEQ) / 64, 256, 0, stream>>>(h2buf, Wfcb, bfc, out);
}

// Round 5
// 4816.562 us; speedup vs baseline: 1.0693x; 1.0693x over previous
//
#include <hip/hip_runtime.h>
#include <hip/hip_bf16.h>

typedef __bf16 bf16_t;
typedef bf16_t bf16x8 __attribute__((ext_vector_type(8)));
typedef float f32x4 __attribute__((ext_vector_type(4)));
typedef unsigned long long u64;

#define T_SEQ 512
#define NB 128
#define HID 1024
#define FIN 64
#define HB (NB * HID)            // 131072 elems = 256 KB per h snapshot
#define NBLK 256                 // 64 L0 + 64 X1 + 128 L1
#define DM 32                    // master h ring depth
#define DX 8                     // X1 partial ring depth
#define X1SLOT (4096 * NB)

// Fragment-contiguous weight LDS: frag*1024B + lane*16B, conflict-free.
#define NF0 136                  // L0 frags: 34 k-chunks x 4 row-tiles
#define NF1 128                  // X1 frags: 32 x 4
#define NFR 64                   // L1 frags: 32 x 2
#define L0_STAGE (NF0 * 64 * 8)  // elems: 69632
#define L1_STAGE (NFR * 64 * 8)  // elems: 32768
// L0 LDS: weights 139264B + stage 4096B + cl 8192B = 151552B
#define LDS_BYTES 151552

#define F0 0      // f0[64]:  L0 block flags
#define FX 64     // fX[64]:  X1 block flags
#define F1 128    // f1[128]: L1 block flags
#define SYNC_N 256

__device__ __forceinline__ float sigm_f(float x) { return 1.0f / (1.0f + __expf(-x)); }
__device__ __forceinline__ float tanh_f(float x) { return 2.0f * sigm_f(2.0f * x) - 1.0f; }

__device__ __forceinline__ unsigned ldcnt(const unsigned* p) {
    return __hip_atomic_load(p, __ATOMIC_RELAXED, __HIP_MEMORY_SCOPE_AGENT);
}
__device__ __forceinline__ void stw32(unsigned* p, unsigned v) {
    __hip_atomic_store(p, v, __ATOMIC_RELAXED, __HIP_MEMORY_SCOPE_AGENT);
}
__device__ __forceinline__ void stwf(float* p, float v) {
    __hip_atomic_store(p, v, __ATOMIC_RELAXED, __HIP_MEMORY_SCOPE_AGENT);
}
__device__ __forceinline__ void stw64(u64* p, u64 v) {
    __hip_atomic_store(p, v, __ATOMIC_RELAXED, __HIP_MEMORY_SCOPE_AGENT);
}

// Fragment-swizzled h layout: 16B unit = (panel*8 + ntile)*64 + lane, holding
// h[n = ntile*16 + (lane&15)][k = panel*32 + (lane>>4)*8 .. +8].

__global__ __launch_bounds__(256) void prep_kernel(
    const float* __restrict__ x,
    const float* __restrict__ Wih0, const float* __restrict__ Whh0,
    const float* __restrict__ bih0, const float* __restrict__ bhh0,
    const float* __restrict__ Wih1, const float* __restrict__ Whh1,
    const float* __restrict__ bih1, const float* __restrict__ bhh1,
    const float* __restrict__ Wfc,
    bf16_t* __restrict__ Wf0, bf16_t* __restrict__ Wf1, bf16_t* __restrict__ WfR,
    bf16_t* __restrict__ xswz, bf16_t* __restrict__ Wfcb,
    float* __restrict__ bias0, float* __restrict__ bias1,
    bf16_t* __restrict__ mh0, bf16_t* __restrict__ mh1,
    unsigned* __restrict__ sync)
{
    const unsigned stride = gridDim.x * blockDim.x;
    const unsigned i0 = blockIdx.x * blockDim.x + threadIdx.x;

    for (unsigned i = i0; i < SYNC_N; i += stride) sync[i] = 0u;

    for (unsigned i = i0; i < 64u * NF0 * 64u; i += stride) {
        unsigned g0 = i / (NF0 * 64u), rem = i % (NF0 * 64u);
        unsigned f = rem >> 6, ln = rem & 63u;
        unsigned pc = f >> 2, mt = f & 3u;
        unsigned r = mt * 16u + (ln & 15u);
        unsigned row = (r & 3u) * HID + g0 * 16u + (r >> 2);
        unsigned k0 = pc * 32u + (ln >> 4) * 8u;
        bf16_t* dst = Wf0 + (size_t)i * 8;
#pragma unroll
        for (int e = 0; e < 8; ++e) {
            unsigned k = k0 + e;
            float v = (k < FIN) ? Wih0[(size_t)row * FIN + k]
                                : Whh0[(size_t)row * HID + (k - FIN)];
            dst[e] = (bf16_t)v;
        }
    }
    for (unsigned i = i0; i < 64u * NF1 * 64u; i += stride) {
        unsigned g = i >> 13, rem = i & 8191u;
        unsigned f = rem >> 6, ln = rem & 63u;
        unsigned pc = f >> 2, mt = f & 3u;
        unsigned r = mt * 16u + (ln & 15u);
        unsigned row = (r & 3u) * HID + g * 16u + (r >> 2);
        unsigned k0 = pc * 32u + (ln >> 4) * 8u;
        bf16_t* dst = Wf1 + (size_t)i * 8;
#pragma unroll
        for (int e = 0; e < 8; ++e)
            dst[e] = (bf16_t)Wih1[(size_t)row * HID + k0 + e];
    }
    for (unsigned i = i0; i < 128u * NFR * 64u; i += stride) {
        unsigned g1 = i >> 12, rem = i & 4095u;
        unsigned f = rem >> 6, ln = rem & 63u;
        unsigned pc = f >> 1, mt = f & 1u;
        unsigned r = mt * 16u + (ln & 15u);
        unsigned row = (r & 3u) * HID + g1 * 8u + (r >> 2);
        unsigned k0 = pc * 32u + (ln >> 4) * 8u;
        bf16_t* dst = WfR + (size_t)i * 8;
#pragma unroll
        for (int e = 0; e < 8; ++e)
            dst[e] = (bf16_t)Whh1[(size_t)row * HID + k0 + e];
    }
    for (unsigned i = i0; i < 4194304u; i += stride) {
        unsigned e = i & 7u, unit = i >> 3;
        unsigned lane = unit & 63u, g = unit >> 6;
        unsigned wvv = g & 7u, pt = g >> 3;
        unsigned p = pt & 1u, t = pt >> 1;
        unsigned n = wvv * 16u + (lane & 15u);
        unsigned k = p * 32u + (lane >> 4) * 8u + e;
        xswz[i] = (bf16_t)x[((size_t)n * T_SEQ + t) * FIN + k];
    }
    for (unsigned i = i0; i < 64u * HID; i += stride)
        Wfcb[i] = (bf16_t)Wfc[i];
    for (unsigned i = i0; i < (unsigned)(DM * HB); i += stride) {
        mh0[i] = (bf16_t)0.0f; mh1[i] = (bf16_t)0.0f;
    }
    for (unsigned i = i0; i < 4096u; i += stride) {
        bias0[i] = bih0[i] + bhh0[i];
        bias1[i] = bih1[i] + bhh1[i];
    }
}

// Persistent cooperative kernel, 256 blocks x 512 threads, 1 block/CU.
// L0/X1 wave mapping = (Mw=32, Nw=32): wave (mh=wv>>2, nh=wv&3) owns m-tiles
// {2mh,2mh+1} x n-tiles {2nh,2nh+1}: each LDS A-fragment read feeds 2 MFMAs,
// halving per-CU LDS volume (1.09 MB -> 545 KB per step) -- LDS pipe was the
// serial-chain bottleneck. Whole-step gating, wv0-only polls (R2 style).
__global__ __launch_bounds__(512) void lstm_persist(
    const bf16_t* __restrict__ Wf0, const bf16_t* __restrict__ Wf1,
    const bf16_t* __restrict__ WfR,
    const float* __restrict__ bias0, const float* __restrict__ bias1,
    const bf16_t* __restrict__ xswz,
    bf16_t* __restrict__ mh0, bf16_t* __restrict__ mh1,
    bf16_t* __restrict__ h2buf,
    float* __restrict__ x1r,
    unsigned* __restrict__ sync)
{
    extern __shared__ bf16_t Wl[];
    const int b = blockIdx.x;
    const int tid = threadIdx.x;
    const int wv = tid >> 6;
    const int lane = tid & 63;
    const int q = lane >> 4;
    const int l = lane & 15;

    if (b < 64) {
        // ================= L0: layer-0 recurrence =================
        const int g0 = b;
        const int mh = wv >> 2, nh = wv & 3;
        const int nt0 = nh * 2, nt1 = nh * 2 + 1;
        for (int c = tid; c < NF0 * 64; c += 512)
            *(bf16x8*)(Wl + (size_t)c * 8) =
                *(const bf16x8*)(Wf0 + ((size_t)g0 * (NF0 * 64) + c) * 8);
        bf16_t* stage = Wl + L0_STAGE;
        float* cl = (float*)(Wl + L0_STAGE + 2048);      // [16][NB]
        for (int i = tid; i < 16 * NB; i += 512) cl[i] = 0.0f;
        float bj[2][4];
#pragma unroll
        for (int mti = 0; mti < 2; ++mti) {
            const int j = g0 * 16 + (mh * 2 + mti) * 4 + q;
#pragma unroll
            for (int gg = 0; gg < 4; ++gg) bj[mti][gg] = bias0[gg * HID + j];
        }
        __syncthreads();

        for (int t = 0; t < T_SEQ; ++t) {
            f32x4 acc[2][2] = {{{0.f,0.f,0.f,0.f},{0.f,0.f,0.f,0.f}},
                               {{0.f,0.f,0.f,0.f},{0.f,0.f,0.f,0.f}}};
            {   // x panels (pc 0,1): no dependency, before the wait
                const bf16_t* X = xswz + (size_t)t * 8192;
#pragma unroll
                for (int p = 0; p < 2; ++p) {
                    bf16x8 av0 = *(const bf16x8*)(Wl + ((size_t)(p * 4 + mh * 2) * 64 + lane) * 8);
                    bf16x8 av1 = *(const bf16x8*)(Wl + ((size_t)(p * 4 + mh * 2 + 1) * 64 + lane) * 8);
                    bf16x8 bv0 = *(const bf16x8*)(X + (((size_t)p * 8 + nt0) * 64 + lane) * 8);
                    bf16x8 bv1 = *(const bf16x8*)(X + (((size_t)p * 8 + nt1) * 64 + lane) * 8);
                    acc[0][0] = __builtin_amdgcn_mfma_f32_16x16x32_bf16(av0, bv0, acc[0][0], 0, 0, 0);
                    acc[0][1] = __builtin_amdgcn_mfma_f32_16x16x32_bf16(av0, bv1, acc[0][1], 0, 0, 0);
                    acc[1][0] = __builtin_amdgcn_mfma_f32_16x16x32_bf16(av1, bv0, acc[1][0], 0, 0, 0);
                    acc[1][1] = __builtin_amdgcn_mfma_f32_16x16x32_bf16(av1, bv1, acc[1][1], 0, 0, 0);
                }
            }
            // wait: f0 all >= t (own chain); fX all >= t-31 (mh0 slot reuse)
            if (wv == 0) {
                const unsigned tA = (unsigned)t;
                const unsigned tB = (t >= DM) ? (unsigned)(t - (DM - 1)) : 0u;
                for (;;) {
                    bool ok = (ldcnt(&sync[F0 + lane]) >= tA)
                           && (ldcnt(&sync[FX + lane]) >= tB);
                    if (__all(ok)) break;
                    __builtin_amdgcn_s_sleep(1);
                }
            }
            __syncthreads();
            // h panels from mh0[t-1]
            {
                const bf16_t* B = mh0 + (size_t)((t + DM - 1) & (DM - 1)) * HB;
                bf16x8 bb0[8], bb1[8];
#pragma unroll
                for (int i = 0; i < 8; ++i) {
                    bb0[i] = *(const bf16x8*)(B + (((size_t)i * 8 + nt0) * 64 + lane) * 8);
                    bb1[i] = *(const bf16x8*)(B + (((size_t)i * 8 + nt1) * 64 + lane) * 8);
                }
#pragma unroll
                for (int p = 0; p < 32; ++p) {
                    bf16x8 av0 = *(const bf16x8*)(Wl + ((size_t)((2 + p) * 4 + mh * 2) * 64 + lane) * 8);
                    bf16x8 av1 = *(const bf16x8*)(Wl + ((size_t)((2 + p) * 4 + mh * 2 + 1) * 64 + lane) * 8);
                    acc[0][0] = __builtin_amdgcn_mfma_f32_16x16x32_bf16(av0, bb0[p & 7], acc[0][0], 0, 0, 0);
                    acc[0][1] = __builtin_amdgcn_mfma_f32_16x16x32_bf16(av0, bb1[p & 7], acc[0][1], 0, 0, 0);
                    acc[1][0] = __builtin_amdgcn_mfma_f32_16x16x32_bf16(av1, bb0[p & 7], acc[1][0], 0, 0, 0);
                    acc[1][1] = __builtin_amdgcn_mfma_f32_16x16x32_bf16(av1, bb1[p & 7], acc[1][1], 0, 0, 0);
                    if (p + 8 < 32) {
                        bb0[p & 7] = *(const bf16x8*)(B + (((size_t)(p + 8) * 8 + nt0) * 64 + lane) * 8);
                        bb1[p & 7] = *(const bf16x8*)(B + (((size_t)(p + 8) * 8 + nt1) * 64 + lane) * 8);
                    }
                }
            }
            // cell update (c in LDS) -> stage
#pragma unroll
            for (int mti = 0; mti < 2; ++mti) {
                const int u = (mh * 2 + mti) * 4 + q;
#pragma unroll
                for (int nti = 0; nti < 2; ++nti) {
                    const int n = (nh * 2 + nti) * 16 + l;
                    float iv = sigm_f(acc[mti][nti][0] + bj[mti][0]);
                    float fv = sigm_f(acc[mti][nti][1] + bj[mti][1]);
                    float gv = tanh_f(acc[mti][nti][2] + bj[mti][2]);
                    float ov = sigm_f(acc[mti][nti][3] + bj[mti][3]);
                    float cn = fv * cl[u * NB + n] + iv * gv;
                    cl[u * NB + n] = cn;
                    stage[n * 16 + u] = (bf16_t)(ov * tanh_f(cn));
                }
            }
            __syncthreads();
            if (tid < 256) {   // master write, swizzled, write-through
                const int n = tid >> 1, half = tid & 1;
                u64 v0 = *(const u64*)(stage + n * 16 + half * 8);
                u64 v1 = *(const u64*)(stage + n * 16 + half * 8 + 4);
                size_t unit = ((size_t)((g0 >> 1) * 8 + (n >> 4))) * 64
                              + ((g0 & 1) * 2 + half) * 16 + (n & 15);
                u64* dst = (u64*)(mh0 + (size_t)(t & (DM - 1)) * HB) + unit * 2;
                stw64(dst, v0); stw64(dst + 1, v1);
            }
            __syncthreads();   // drain
            if (tid == 0) stw32(&sync[F0 + g0], (unsigned)(t + 1));
        }
    } else if (b < 128) {
        // ================= X1: W_ih1 @ h0[t] partials =================
        const int g = b - 64;
        const int mh = wv >> 2, nh = wv & 3;
        const int nt0 = nh * 2, nt1 = nh * 2 + 1;
        for (int c = tid; c < NF1 * 64; c += 512)
            *(bf16x8*)(Wl + (size_t)c * 8) =
                *(const bf16x8*)(Wf1 + ((size_t)g * (NF1 * 64) + c) * 8);
        __syncthreads();

        for (int t = 0; t < T_SEQ; ++t) {
            // wait: f0 all >= t+1 (h0[t] ready); f1 all >= t-(DX-1) (ring guard)
            if (wv == 0) {
                const unsigned tA = (unsigned)(t + 1);
                const unsigned tC = (t >= DX) ? (unsigned)(t - (DX - 1)) : 0u;
                for (;;) {
                    bool ok = (ldcnt(&sync[F0 + lane]) >= tA)
                           && (ldcnt(&sync[F1 + lane]) >= tC)
                           && (ldcnt(&sync[F1 + 64 + lane]) >= tC);
                    if (__all(ok)) break;
                    __builtin_amdgcn_s_sleep(1);
                }
            }
            __syncthreads();
            f32x4 acc[2][2] = {{{0.f,0.f,0.f,0.f},{0.f,0.f,0.f,0.f}},
                               {{0.f,0.f,0.f,0.f},{0.f,0.f,0.f,0.f}}};
            {
                const bf16_t* B = mh0 + (size_t)(t & (DM - 1)) * HB;
                bf16x8 bb0[8], bb1[8];
#pragma unroll
                for (int i = 0; i < 8; ++i) {
                    bb0[i] = *(const bf16x8*)(B + (((size_t)i * 8 + nt0) * 64 + lane) * 8);
                    bb1[i] = *(const bf16x8*)(B + (((size_t)i * 8 + nt1) * 64 + lane) * 8);
                }
#pragma unroll
                for (int p = 0; p < 32; ++p) {
                    bf16x8 av0 = *(const bf16x8*)(Wl + ((size_t)(p * 4 + mh * 2) * 64 + lane) * 8);
                    bf16x8 av1 = *(const bf16x8*)(Wl + ((size_t)(p * 4 + mh * 2 + 1) * 64 + lane) * 8);
                    acc[0][0] = __builtin_amdgcn_mfma_f32_16x16x32_bf16(av0, bb0[p & 7], acc[0][0], 0, 0, 0);
                    acc[0][1] = __builtin_amdgcn_mfma_f32_16x16x32_bf16(av0, bb1[p & 7], acc[0][1], 0, 0, 0);
                    acc[1][0] = __builtin_amdgcn_mfma_f32_16x16x32_bf16(av1, bb0[p & 7], acc[1][0], 0, 0, 0);
                    acc[1][1] = __builtin_amdgcn_mfma_f32_16x16x32_bf16(av1, bb1[p & 7], acc[1][1], 0, 0, 0);
                    if (p + 8 < 32) {
                        bb0[p & 7] = *(const bf16x8*)(B + (((size_t)(p + 8) * 8 + nt0) * 64 + lane) * 8);
                        bb1[p & 7] = *(const bf16x8*)(B + (((size_t)(p + 8) * 8 + nt1) * 64 + lane) * 8);
                    }
                }
            }
            {   // scatter partials: row = u_loc*4 + gate, col = batch
                float* P = x1r + (size_t)(t & (DX - 1)) * X1SLOT + (size_t)g * 64 * NB;
#pragma unroll
                for (int mti = 0; mti < 2; ++mti) {
                    const int u = (mh * 2 + mti) * 4 + q;
#pragma unroll
                    for (int nti = 0; nti < 2; ++nti) {
                        const int n = (nh * 2 + nti) * 16 + l;
#pragma unroll
                        for (int jj = 0; jj < 4; ++jj)
                            stwf(P + (size_t)(u * 4 + jj) * NB + n, acc[mti][nti][jj]);
                    }
                }
            }
            __syncthreads();   // drain partial stores
            if (tid == 0) stw32(&sync[FX + g], (unsigned)(t + 1));
        }
    } else {
        // ================= L1: layer-1 recurrent half =================
        const int g1 = b - 128;
        const int nn = wv * 16 + l;
        for (int c = tid; c < NFR * 64; c += 512)
            *(bf16x8*)(Wl + (size_t)c * 8) =
                *(const bf16x8*)(WfR + ((size_t)g1 * (NFR * 64) + c) * 8);
        bf16_t* stage = Wl + L1_STAGE;
        float* cl = (float*)(Wl + L1_STAGE + 1024);      // [8][NB]
        for (int i = tid; i < 8 * NB; i += 512) cl[i] = 0.0f;
        float bj[2][4];
#pragma unroll
        for (int mt = 0; mt < 2; ++mt) {
            const int j = g1 * 8 + mt * 4 + q;
#pragma unroll
            for (int gg = 0; gg < 4; ++gg) bj[mt][gg] = bias1[gg * HID + j];
        }
        __syncthreads();

        for (int t = 0; t < T_SEQ; ++t) {
            // wait: fX[g1>>1] >= t+1 (partials ready); f1 all >= t (own chain)
            if (wv == 0) {
                const unsigned tA = (unsigned)(t + 1);
                const unsigned tO = (unsigned)t;
                const unsigned gx = (unsigned)(g1 >> 1);
                for (;;) {
                    bool ok = (ldcnt(&sync[FX + gx]) >= tA)
                           && (ldcnt(&sync[F1 + lane]) >= tO)
                           && (ldcnt(&sync[F1 + 64 + lane]) >= tO);
                    if (__all(ok)) break;
                    __builtin_amdgcn_s_sleep(1);
                }
            }
            __syncthreads();
            // partials early (latency hides under the panel loop)
            float pv[2][4];
            {
                const float* P = x1r + (size_t)(t & (DX - 1)) * X1SLOT + (size_t)g1 * 32 * NB;
#pragma unroll
                for (int mt = 0; mt < 2; ++mt)
#pragma unroll
                    for (int jj = 0; jj < 4; ++jj)
                        pv[mt][jj] = P[(size_t)((mt * 4 + q) * 4 + jj) * NB + nn];
            }
            f32x4 acc[2] = {{0.f,0.f,0.f,0.f},{0.f,0.f,0.f,0.f}};
            {
                const bf16_t* B1 = mh1 + (size_t)((t + DM - 1) & (DM - 1)) * HB;
                bf16x8 bb[16];
#pragma unroll
                for (int i = 0; i < 16; ++i)
                    bb[i] = *(const bf16x8*)(B1 + (((size_t)i * 8 + wv) * 64 + lane) * 8);
#pragma unroll
                for (int p = 0; p < 32; ++p) {
                    bf16x8 bv = bb[p & 15];
#pragma unroll
                    for (int mt = 0; mt < 2; ++mt) {
                        bf16x8 av = *(const bf16x8*)(Wl + ((size_t)(p * 2 + mt) * 64 + lane) * 8);
                        acc[mt] = __builtin_amdgcn_mfma_f32_16x16x32_bf16(av, bv, acc[mt], 0, 0, 0);
                    }
                    if (p + 16 < 32)
                        bb[p & 15] = *(const bf16x8*)(B1 + (((size_t)(p + 16) * 8 + wv) * 64 + lane) * 8);
                }
            }
#pragma unroll
            for (int mt = 0; mt < 2; ++mt) {
                const int u = mt * 4 + q;
                float iv = sigm_f(acc[mt][0] + pv[mt][0] + bj[mt][0]);
                float fv = sigm_f(acc[mt][1] + pv[mt][1] + bj[mt][1]);
                float gv = tanh_f(acc[mt][2] + pv[mt][2] + bj[mt][2]);
                float ov = sigm_f(acc[mt][3] + pv[mt][3] + bj[mt][3]);
                float cn = fv * cl[u * NB + nn] + iv * gv;
                cl[u * NB + nn] = cn;
                stage[nn * 8 + u] = (bf16_t)(ov * tanh_f(cn));
            }
            __asm__ volatile("s_waitcnt lgkmcnt(0)" ::: "memory");  // own-wave LDS done
            u64 v = 0;
            if (q < 2) {   // per-wave master write (stage rows are wave-owned)
                v = *(const u64*)(stage + (size_t)(wv * 16 + l) * 8 + q * 4);
                size_t unit = ((size_t)(g1 >> 2) * 8 + wv) * 64 + (size_t)(g1 & 3) * 16 + l;
                stw64((u64*)(mh1 + (size_t)(t & (DM - 1)) * HB) + unit * 2 + q, v);
            }
            __syncthreads();   // drain all waves' master stores
            if (tid == 0) stw32(&sync[F1 + g1], (unsigned)(t + 1));
            if (q < 2)     // h2 history after flag (off the chain)
                *(u64*)(h2buf + ((size_t)(wv * 16 + l) * T_SEQ + t) * HID + g1 * 8 + q * 4) = v;
        }
    }
}

__global__ __launch_bounds__(256) void fc_kernel(
    const bf16_t* __restrict__ h2buf, const bf16_t* __restrict__ Wfcb,
    const float* __restrict__ bfc, float* __restrict__ out)
{
    const int tid = threadIdx.x, wv = tid >> 6, lane = tid & 63;
    const int q = lane >> 4, l = lane & 15;
    const int m0 = blockIdx.x * 64 + wv * 16;
    const bf16_t* arow = h2buf + (size_t)(m0 + l) * HID + q * 8;
    const bf16_t* brow = Wfcb + (size_t)l * HID + q * 8;
    f32x4 acc[4] = {{0.f,0.f,0.f,0.f},{0.f,0.f,0.f,0.f},{0.f,0.f,0.f,0.f},{0.f,0.f,0.f,0.f}};
#pragma unroll 4
    for (int p = 0; p < 32; ++p) {
        bf16x8 av = *(const bf16x8*)(arow + p * 32);
#pragma unroll
        for (int ntile = 0; ntile < 4; ++ntile) {
            bf16x8 bv = *(const bf16x8*)(brow + (size_t)ntile * 16 * HID + p * 32);
            acc[ntile] = __builtin_amdgcn_mfma_f32_16x16x32_bf16(av, bv, acc[ntile], 0, 0, 0);
        }
    }
#pragma unroll
    for (int ntile = 0; ntile < 4; ++ntile) {
        float bv = bfc[ntile * 16 + l];
#pragma unroll
        for (int r = 0; r < 4; ++r)
            out[(size_t)(m0 + q * 4 + r) * 64 + ntile * 16 + l] = acc[ntile][r] + bv;
    }
}

extern "C" void kernel_launch(void* const* d_in, const int* in_sizes, int n_in,
                              void* d_out, int out_size, void* d_ws, size_t ws_size,
                              hipStream_t stream)
{
    const float* x    = (const float*)d_in[0];
    const float* Wih0 = (const float*)d_in[1];
    const float* Whh0 = (const float*)d_in[2];
    const float* bih0 = (const float*)d_in[3];
    const float* bhh0 = (const float*)d_in[4];
    const float* Wih1 = (const float*)d_in[5];
    const float* Whh1 = (const float*)d_in[6];
    const float* bih1 = (const float*)d_in[7];
    const float* bhh1 = (const float*)d_in[8];
    const float* Wfc  = (const float*)d_in[9];
    const float* bfc  = (const float*)d_in[10];
    float* out = (float*)d_out;

    char* ws = (char*)d_ws;
    size_t off = 0;
    auto alloc = [&](size_t bytes) -> void* {
        void* p = ws + off;
        off += (bytes + 255) & ~(size_t)255;
        return p;
    };
    bf16_t* Wf0  = (bf16_t*)alloc((size_t)64 * NF0 * 64 * 8 * 2);
    bf16_t* Wf1  = (bf16_t*)alloc((size_t)64 * NF1 * 64 * 8 * 2);
    bf16_t* WfR  = (bf16_t*)alloc((size_t)128 * NFR * 64 * 8 * 2);
    bf16_t* xswz = (bf16_t*)alloc((size_t)NB * T_SEQ * FIN * 2);
    bf16_t* h2buf= (bf16_t*)alloc((size_t)NB * T_SEQ * HID * 2);
    bf16_t* mh0  = (bf16_t*)alloc((size_t)DM * HB * 2);
    bf16_t* mh1  = (bf16_t*)alloc((size_t)DM * HB * 2);
    float*  x1r  = (float*)alloc((size_t)DX * X1SLOT * 4);
    float*  bias0= (float*)alloc(4096 * 4);
    float*  bias1= (float*)alloc(4096 * 4);
    bf16_t* Wfcb = (bf16_t*)alloc((size_t)64 * HID * 2);
    unsigned* syncp = (unsigned*)alloc(SYNC_N * 4);
    if (off > ws_size) return;

    hipFuncSetAttribute((const void*)lstm_persist,
                        hipFuncAttributeMaxDynamicSharedMemorySize, LDS_BYTES);

    prep_kernel<<<1024, 256, 0, stream>>>(x, Wih0, Whh0, bih0, bhh0,
                                          Wih1, Whh1, bih1, bhh1, Wfc,
                                          Wf0, Wf1, WfR, xswz, Wfcb,
                                          bias0, bias1, mh0, mh1, syncp);

    void* args[] = { (void*)&Wf0, (void*)&Wf1, (void*)&WfR,
                     (void*)&bias0, (void*)&bias1,
                     (void*)&xswz, (void*)&mh0, (void*)&mh1,
                     (void*)&h2buf, (void*)&x1r,
                     (void*)&syncp };
    hipLaunchCooperativeKernel((void*)lstm_persist, dim3(NBLK), dim3(512),
                               args, LDS_BYTES, stream);

    fc_kernel<<<(NB * T_SEQ) / 64, 256, 0, stream>>>(h2buf, Wfcb, bfc, out);
}

// Round 6
// 4773.569 us; speedup vs baseline: 1.0789x; 1.0090x over previous
//
#include <hip/hip_runtime.h>
#include <hip/hip_bf16.h>

typedef __bf16 bf16_t;
typedef bf16_t bf16x8 __attribute__((ext_vector_type(8)));
typedef float f32x4 __attribute__((ext_vector_type(4)));
typedef unsigned long long u64;

#define T_SEQ 512
#define NB 128
#define HID 1024
#define FIN 64
#define HB (NB * HID)            // 131072 elems = 256 KB per h snapshot
#define NBLK 256                 // 64 L0 + 64 X1 + 128 L1
#define DM 32                    // master h ring depth
#define DX 8                     // X1 partial ring depth
#define X1SLOT (4096 * NB)

// Fragment-contiguous weight LDS: frag*1024B + lane*16B, conflict-free.
#define NF0 136                  // L0 frags: 34 k-chunks x 4 row-tiles
#define NF1 128                  // X1 frags: 32 x 4
#define NFR 64                   // L1 frags: 32 x 2
#define L0_STAGE (NF0 * 64 * 8)  // elems: 69632
#define L1_STAGE (NFR * 64 * 8)  // elems: 32768
// L0 LDS: weights 139264B + stage 4096B + cl 8192B = 151552B
#define LDS_BYTES 151552

#define F0 0      // f0[64]:  L0 block flags
#define FX 64     // fX[64]:  X1 block flags
#define F1 128    // f1[128]: L1 block flags
#define SYNC_N 256

__device__ __forceinline__ float sigm_f(float x) { return 1.0f / (1.0f + __expf(-x)); }
__device__ __forceinline__ float tanh_f(float x) { return 2.0f * sigm_f(2.0f * x) - 1.0f; }

__device__ __forceinline__ unsigned ldcnt(const unsigned* p) {
    return __hip_atomic_load(p, __ATOMIC_RELAXED, __HIP_MEMORY_SCOPE_AGENT);
}
__device__ __forceinline__ void stw32(unsigned* p, unsigned v) {
    __hip_atomic_store(p, v, __ATOMIC_RELAXED, __HIP_MEMORY_SCOPE_AGENT);
}
__device__ __forceinline__ void stwf(float* p, float v) {
    __hip_atomic_store(p, v, __ATOMIC_RELAXED, __HIP_MEMORY_SCOPE_AGENT);
}
__device__ __forceinline__ void stw64(u64* p, u64 v) {
    __hip_atomic_store(p, v, __ATOMIC_RELAXED, __HIP_MEMORY_SCOPE_AGENT);
}

// Fragment-swizzled h layout: 16B unit = (panel*8 + ntile)*64 + lane, holding
// h[n = ntile*16 + (lane&15)][k = panel*32 + (lane>>4)*8 .. +8].

__global__ __launch_bounds__(256) void prep_kernel(
    const float* __restrict__ x,
    const float* __restrict__ Wih0, const float* __restrict__ Whh0,
    const float* __restrict__ bih0, const float* __restrict__ bhh0,
    const float* __restrict__ Wih1, const float* __restrict__ Whh1,
    const float* __restrict__ bih1, const float* __restrict__ bhh1,
    const float* __restrict__ Wfc,
    bf16_t* __restrict__ Wf0, bf16_t* __restrict__ Wf1, bf16_t* __restrict__ WfR,
    bf16_t* __restrict__ xswz, bf16_t* __restrict__ Wfcb,
    float* __restrict__ bias0, float* __restrict__ bias1,
    bf16_t* __restrict__ mh0, bf16_t* __restrict__ mh1,
    unsigned* __restrict__ sync)
{
    const unsigned stride = gridDim.x * blockDim.x;
    const unsigned i0 = blockIdx.x * blockDim.x + threadIdx.x;

    for (unsigned i = i0; i < SYNC_N; i += stride) sync[i] = 0u;

    for (unsigned i = i0; i < 64u * NF0 * 64u; i += stride) {
        unsigned g0 = i / (NF0 * 64u), rem = i % (NF0 * 64u);
        unsigned f = rem >> 6, ln = rem & 63u;
        unsigned pc = f >> 2, mt = f & 3u;
        unsigned r = mt * 16u + (ln & 15u);
        unsigned row = (r & 3u) * HID + g0 * 16u + (r >> 2);
        unsigned k0 = pc * 32u + (ln >> 4) * 8u;
        bf16_t* dst = Wf0 + (size_t)i * 8;
#pragma unroll
        for (int e = 0; e < 8; ++e) {
            unsigned k = k0 + e;
            float v = (k < FIN) ? Wih0[(size_t)row * FIN + k]
                                : Whh0[(size_t)row * HID + (k - FIN)];
            dst[e] = (bf16_t)v;
        }
    }
    for (unsigned i = i0; i < 64u * NF1 * 64u; i += stride) {
        unsigned g = i >> 13, rem = i & 8191u;
        unsigned f = rem >> 6, ln = rem & 63u;
        unsigned pc = f >> 2, mt = f & 3u;
        unsigned r = mt * 16u + (ln & 15u);
        unsigned row = (r & 3u) * HID + g * 16u + (r >> 2);
        unsigned k0 = pc * 32u + (ln >> 4) * 8u;
        bf16_t* dst = Wf1 + (size_t)i * 8;
#pragma unroll
        for (int e = 0; e < 8; ++e)
            dst[e] = (bf16_t)Wih1[(size_t)row * HID + k0 + e];
    }
    for (unsigned i = i0; i < 128u * NFR * 64u; i += stride) {
        unsigned g1 = i >> 12, rem = i & 4095u;
        unsigned f = rem >> 6, ln = rem & 63u;
        unsigned pc = f >> 1, mt = f & 1u;
        unsigned r = mt * 16u + (ln & 15u);
        unsigned row = (r & 3u) * HID + g1 * 8u + (r >> 2);
        unsigned k0 = pc * 32u + (ln >> 4) * 8u;
        bf16_t* dst = WfR + (size_t)i * 8;
#pragma unroll
        for (int e = 0; e < 8; ++e)
            dst[e] = (bf16_t)Whh1[(size_t)row * HID + k0 + e];
    }
    for (unsigned i = i0; i < 4194304u; i += stride) {
        unsigned e = i & 7u, unit = i >> 3;
        unsigned lane = unit & 63u, g = unit >> 6;
        unsigned wvv = g & 7u, pt = g >> 3;
        unsigned p = pt & 1u, t = pt >> 1;
        unsigned n = wvv * 16u + (lane & 15u);
        unsigned k = p * 32u + (lane >> 4) * 8u + e;
        xswz[i] = (bf16_t)x[((size_t)n * T_SEQ + t) * FIN + k];
    }
    for (unsigned i = i0; i < 64u * HID; i += stride)
        Wfcb[i] = (bf16_t)Wfc[i];
    for (unsigned i = i0; i < (unsigned)(DM * HB); i += stride) {
        mh0[i] = (bf16_t)0.0f; mh1[i] = (bf16_t)0.0f;
    }
    for (unsigned i = i0; i < 4096u; i += stride) {
        bias0[i] = bih0[i] + bhh0[i];
        bias1[i] = bih1[i] + bhh1[i];
    }
}

// Persistent cooperative kernel, 256 blocks x 512 threads, 1 block/CU.
// __launch_bounds__(512, 2): declare 2 waves/EU so the allocator may use the
// full 256-VGPR budget -- prior builds compressed the h-panel prefetch buffers
// to ~3-4 in flight (VGPR_Count 52/88/68), leaving the L3-latency (~700cy) of
// the broadcast stream exposed ~34x per step. Depth-16/32 explicit prefetch
// puts 16-32KB per wave in flight (>> BW*latency = 50KB/CU across 8 waves).
__global__ __launch_bounds__(512, 2) void lstm_persist(
    const bf16_t* __restrict__ Wf0, const bf16_t* __restrict__ Wf1,
    const bf16_t* __restrict__ WfR,
    const float* __restrict__ bias0, const float* __restrict__ bias1,
    const bf16_t* __restrict__ xswz,
    bf16_t* __restrict__ mh0, bf16_t* __restrict__ mh1,
    bf16_t* __restrict__ h2buf,
    float* __restrict__ x1r,
    unsigned* __restrict__ sync)
{
    extern __shared__ bf16_t Wl[];
    const int b = blockIdx.x;
    const int tid = threadIdx.x;
    const int wv = tid >> 6;
    const int lane = tid & 63;
    const int q = lane >> 4;
    const int l = lane & 15;

    if (b < 64) {
        // ================= L0: layer-0 recurrence =================
        const int g0 = b;
        const int mh = wv >> 2, nh = wv & 3;
        const int nt0 = nh * 2, nt1 = nh * 2 + 1;
        for (int c = tid; c < NF0 * 64; c += 512)
            *(bf16x8*)(Wl + (size_t)c * 8) =
                *(const bf16x8*)(Wf0 + ((size_t)g0 * (NF0 * 64) + c) * 8);
        bf16_t* stage = Wl + L0_STAGE;
        float* cl = (float*)(Wl + L0_STAGE + 2048);      // [16][NB]
        for (int i = tid; i < 16 * NB; i += 512) cl[i] = 0.0f;
        float bj[2][4];
#pragma unroll
        for (int mti = 0; mti < 2; ++mti) {
            const int j = g0 * 16 + (mh * 2 + mti) * 4 + q;
#pragma unroll
            for (int gg = 0; gg < 4; ++gg) bj[mti][gg] = bias0[gg * HID + j];
        }
        __syncthreads();

        for (int t = 0; t < T_SEQ; ++t) {
            f32x4 acc[2][2] = {{{0.f,0.f,0.f,0.f},{0.f,0.f,0.f,0.f}},
                               {{0.f,0.f,0.f,0.f},{0.f,0.f,0.f,0.f}}};
            {   // x panels (pc 0,1): no dependency, before the wait
                const bf16_t* X = xswz + (size_t)t * 8192;
#pragma unroll
                for (int p = 0; p < 2; ++p) {
                    bf16x8 av0 = *(const bf16x8*)(Wl + ((size_t)(p * 4 + mh * 2) * 64 + lane) * 8);
                    bf16x8 av1 = *(const bf16x8*)(Wl + ((size_t)(p * 4 + mh * 2 + 1) * 64 + lane) * 8);
                    bf16x8 bv0 = *(const bf16x8*)(X + (((size_t)p * 8 + nt0) * 64 + lane) * 8);
                    bf16x8 bv1 = *(const bf16x8*)(X + (((size_t)p * 8 + nt1) * 64 + lane) * 8);
                    acc[0][0] = __builtin_amdgcn_mfma_f32_16x16x32_bf16(av0, bv0, acc[0][0], 0, 0, 0);
                    acc[0][1] = __builtin_amdgcn_mfma_f32_16x16x32_bf16(av0, bv1, acc[0][1], 0, 0, 0);
                    acc[1][0] = __builtin_amdgcn_mfma_f32_16x16x32_bf16(av1, bv0, acc[1][0], 0, 0, 0);
                    acc[1][1] = __builtin_amdgcn_mfma_f32_16x16x32_bf16(av1, bv1, acc[1][1], 0, 0, 0);
                }
            }
            // wait: f0 all >= t (own chain); fX all >= t-31 (mh0 slot reuse)
            if (wv == 0) {
                const unsigned tA = (unsigned)t;
                const unsigned tB = (t >= DM) ? (unsigned)(t - (DM - 1)) : 0u;
                for (;;) {
                    bool ok = (ldcnt(&sync[F0 + lane]) >= tA)
                           && (ldcnt(&sync[FX + lane]) >= tB);
                    if (__all(ok)) break;
                    __builtin_amdgcn_s_sleep(1);
                }
            }
            __syncthreads();
            // h panels from mh0[t-1]: dual streams, depth-16 prefetch
            {
                const bf16_t* B = mh0 + (size_t)((t + DM - 1) & (DM - 1)) * HB;
                bf16x8 bb0[16], bb1[16];
#pragma unroll
                for (int i = 0; i < 16; ++i) {
                    bb0[i] = *(const bf16x8*)(B + (((size_t)i * 8 + nt0) * 64 + lane) * 8);
                    bb1[i] = *(const bf16x8*)(B + (((size_t)i * 8 + nt1) * 64 + lane) * 8);
                }
#pragma unroll
                for (int p = 0; p < 32; ++p) {
                    bf16x8 av0 = *(const bf16x8*)(Wl + ((size_t)((2 + p) * 4 + mh * 2) * 64 + lane) * 8);
                    bf16x8 av1 = *(const bf16x8*)(Wl + ((size_t)((2 + p) * 4 + mh * 2 + 1) * 64 + lane) * 8);
                    acc[0][0] = __builtin_amdgcn_mfma_f32_16x16x32_bf16(av0, bb0[p & 15], acc[0][0], 0, 0, 0);
                    acc[0][1] = __builtin_amdgcn_mfma_f32_16x16x32_bf16(av0, bb1[p & 15], acc[0][1], 0, 0, 0);
                    acc[1][0] = __builtin_amdgcn_mfma_f32_16x16x32_bf16(av1, bb0[p & 15], acc[1][0], 0, 0, 0);
                    acc[1][1] = __builtin_amdgcn_mfma_f32_16x16x32_bf16(av1, bb1[p & 15], acc[1][1], 0, 0, 0);
                    if (p + 16 < 32) {
                        bb0[p & 15] = *(const bf16x8*)(B + (((size_t)(p + 16) * 8 + nt0) * 64 + lane) * 8);
                        bb1[p & 15] = *(const bf16x8*)(B + (((size_t)(p + 16) * 8 + nt1) * 64 + lane) * 8);
                    }
                }
            }
            // cell update (c in LDS) -> stage
#pragma unroll
            for (int mti = 0; mti < 2; ++mti) {
                const int u = (mh * 2 + mti) * 4 + q;
#pragma unroll
                for (int nti = 0; nti < 2; ++nti) {
                    const int n = (nh * 2 + nti) * 16 + l;
                    float iv = sigm_f(acc[mti][nti][0] + bj[mti][0]);
                    float fv = sigm_f(acc[mti][nti][1] + bj[mti][1]);
                    float gv = tanh_f(acc[mti][nti][2] + bj[mti][2]);
                    float ov = sigm_f(acc[mti][nti][3] + bj[mti][3]);
                    float cn = fv * cl[u * NB + n] + iv * gv;
                    cl[u * NB + n] = cn;
                    stage[n * 16 + u] = (bf16_t)(ov * tanh_f(cn));
                }
            }
            __syncthreads();
            if (tid < 256) {   // master write, swizzled, write-through
                const int n = tid >> 1, half = tid & 1;
                u64 v0 = *(const u64*)(stage + n * 16 + half * 8);
                u64 v1 = *(const u64*)(stage + n * 16 + half * 8 + 4);
                size_t unit = ((size_t)((g0 >> 1) * 8 + (n >> 4))) * 64
                              + ((g0 & 1) * 2 + half) * 16 + (n & 15);
                u64* dst = (u64*)(mh0 + (size_t)(t & (DM - 1)) * HB) + unit * 2;
                stw64(dst, v0); stw64(dst + 1, v1);
            }
            __syncthreads();   // drain
            if (tid == 0) stw32(&sync[F0 + g0], (unsigned)(t + 1));
        }
    } else if (b < 128) {
        // ================= X1: W_ih1 @ h0[t] partials =================
        const int g = b - 64;
        const int mh = wv >> 2, nh = wv & 3;
        const int nt0 = nh * 2, nt1 = nh * 2 + 1;
        for (int c = tid; c < NF1 * 64; c += 512)
            *(bf16x8*)(Wl + (size_t)c * 8) =
                *(const bf16x8*)(Wf1 + ((size_t)g * (NF1 * 64) + c) * 8);
        __syncthreads();

        for (int t = 0; t < T_SEQ; ++t) {
            // wait: f0 all >= t+1 (h0[t] ready); f1 all >= t-(DX-1) (ring guard)
            if (wv == 0) {
                const unsigned tA = (unsigned)(t + 1);
                const unsigned tC = (t >= DX) ? (unsigned)(t - (DX - 1)) : 0u;
                for (;;) {
                    bool ok = (ldcnt(&sync[F0 + lane]) >= tA)
                           && (ldcnt(&sync[F1 + lane]) >= tC)
                           && (ldcnt(&sync[F1 + 64 + lane]) >= tC);
                    if (__all(ok)) break;
                    __builtin_amdgcn_s_sleep(1);
                }
            }
            __syncthreads();
            f32x4 acc[2][2] = {{{0.f,0.f,0.f,0.f},{0.f,0.f,0.f,0.f}},
                               {{0.f,0.f,0.f,0.f},{0.f,0.f,0.f,0.f}}};
            {   // h0[t] panels: dual streams, depth-16 prefetch
                const bf16_t* B = mh0 + (size_t)(t & (DM - 1)) * HB;
                bf16x8 bb0[16], bb1[16];
#pragma unroll
                for (int i = 0; i < 16; ++i) {
                    bb0[i] = *(const bf16x8*)(B + (((size_t)i * 8 + nt0) * 64 + lane) * 8);
                    bb1[i] = *(const bf16x8*)(B + (((size_t)i * 8 + nt1) * 64 + lane) * 8);
                }
#pragma unroll
                for (int p = 0; p < 32; ++p) {
                    bf16x8 av0 = *(const bf16x8*)(Wl + ((size_t)(p * 4 + mh * 2) * 64 + lane) * 8);
                    bf16x8 av1 = *(const bf16x8*)(Wl + ((size_t)(p * 4 + mh * 2 + 1) * 64 + lane) * 8);
                    acc[0][0] = __builtin_amdgcn_mfma_f32_16x16x32_bf16(av0, bb0[p & 15], acc[0][0], 0, 0, 0);
                    acc[0][1] = __builtin_amdgcn_mfma_f32_16x16x32_bf16(av0, bb1[p & 15], acc[0][1], 0, 0, 0);
                    acc[1][0] = __builtin_amdgcn_mfma_f32_16x16x32_bf16(av1, bb0[p & 15], acc[1][0], 0, 0, 0);
                    acc[1][1] = __builtin_amdgcn_mfma_f32_16x16x32_bf16(av1, bb1[p & 15], acc[1][1], 0, 0, 0);
                    if (p + 16 < 32) {
                        bb0[p & 15] = *(const bf16x8*)(B + (((size_t)(p + 16) * 8 + nt0) * 64 + lane) * 8);
                        bb1[p & 15] = *(const bf16x8*)(B + (((size_t)(p + 16) * 8 + nt1) * 64 + lane) * 8);
                    }
                }
            }
            {   // scatter partials: row = u_loc*4 + gate, col = batch
                float* P = x1r + (size_t)(t & (DX - 1)) * X1SLOT + (size_t)g * 64 * NB;
#pragma unroll
                for (int mti = 0; mti < 2; ++mti) {
                    const int u = (mh * 2 + mti) * 4 + q;
#pragma unroll
                    for (int nti = 0; nti < 2; ++nti) {
                        const int n = (nh * 2 + nti) * 16 + l;
#pragma unroll
                        for (int jj = 0; jj < 4; ++jj)
                            stwf(P + (size_t)(u * 4 + jj) * NB + n, acc[mti][nti][jj]);
                    }
                }
            }
            __syncthreads();   // drain partial stores
            if (tid == 0) stw32(&sync[FX + g], (unsigned)(t + 1));
        }
    } else {
        // ================= L1: layer-1 recurrent half =================
        const int g1 = b - 128;
        const int nn = wv * 16 + l;
        for (int c = tid; c < NFR * 64; c += 512)
            *(bf16x8*)(Wl + (size_t)c * 8) =
                *(const bf16x8*)(WfR + ((size_t)g1 * (NFR * 64) + c) * 8);
        bf16_t* stage = Wl + L1_STAGE;
        float* cl = (float*)(Wl + L1_STAGE + 1024);      // [8][NB]
        for (int i = tid; i < 8 * NB; i += 512) cl[i] = 0.0f;
        float bj[2][4];
#pragma unroll
        for (int mt = 0; mt < 2; ++mt) {
            const int j = g1 * 8 + mt * 4 + q;
#pragma unroll
            for (int gg = 0; gg < 4; ++gg) bj[mt][gg] = bias1[gg * HID + j];
        }
        __syncthreads();

        for (int t = 0; t < T_SEQ; ++t) {
            // wait: fX[g1>>1] >= t+1 (partials ready); f1 all >= t (own chain)
            if (wv == 0) {
                const unsigned tA = (unsigned)(t + 1);
                const unsigned tO = (unsigned)t;
                const unsigned gx = (unsigned)(g1 >> 1);
                for (;;) {
                    bool ok = (ldcnt(&sync[FX + gx]) >= tA)
                           && (ldcnt(&sync[F1 + lane]) >= tO)
                           && (ldcnt(&sync[F1 + 64 + lane]) >= tO);
                    if (__all(ok)) break;
                    __builtin_amdgcn_s_sleep(1);
                }
            }
            __syncthreads();
            // partials early (latency hides under the panel loop)
            float pv[2][4];
            {
                const float* P = x1r + (size_t)(t & (DX - 1)) * X1SLOT + (size_t)g1 * 32 * NB;
#pragma unroll
                for (int mt = 0; mt < 2; ++mt)
#pragma unroll
                    for (int jj = 0; jj < 4; ++jj)
                        pv[mt][jj] = P[(size_t)((mt * 4 + q) * 4 + jj) * NB + nn];
            }
            f32x4 acc[2] = {{0.f,0.f,0.f,0.f},{0.f,0.f,0.f,0.f}};
            {   // h1[t-1]: all 32 panels upfront (full-depth prefetch, 128 VGPR)
                const bf16_t* B1 = mh1 + (size_t)((t + DM - 1) & (DM - 1)) * HB;
                bf16x8 bb[32];
#pragma unroll
                for (int i = 0; i < 32; ++i)
                    bb[i] = *(const bf16x8*)(B1 + (((size_t)i * 8 + wv) * 64 + lane) * 8);
#pragma unroll
                for (int p = 0; p < 32; ++p) {
#pragma unroll
                    for (int mt = 0; mt < 2; ++mt) {
                        bf16x8 av = *(const bf16x8*)(Wl + ((size_t)(p * 2 + mt) * 64 + lane) * 8);
                        acc[mt] = __builtin_amdgcn_mfma_f32_16x16x32_bf16(av, bb[p], acc[mt], 0, 0, 0);
                    }
                }
            }
#pragma unroll
            for (int mt = 0; mt < 2; ++mt) {
                const int u = mt * 4 + q;
                float iv = sigm_f(acc[mt][0] + pv[mt][0] + bj[mt][0]);
                float fv = sigm_f(acc[mt][1] + pv[mt][1] + bj[mt][1]);
                float gv = tanh_f(acc[mt][2] + pv[mt][2] + bj[mt][2]);
                float ov = sigm_f(acc[mt][3] + pv[mt][3] + bj[mt][3]);
                float cn = fv * cl[u * NB + nn] + iv * gv;
                cl[u * NB + nn] = cn;
                stage[nn * 8 + u] = (bf16_t)(ov * tanh_f(cn));
            }
            __asm__ volatile("s_waitcnt lgkmcnt(0)" ::: "memory");  // own-wave LDS done
            u64 v = 0;
            if (q < 2) {   // per-wave master write (stage rows are wave-owned)
                v = *(const u64*)(stage + (size_t)(wv * 16 + l) * 8 + q * 4);
                size_t unit = ((size_t)(g1 >> 2) * 8 + wv) * 64 + (size_t)(g1 & 3) * 16 + l;
                stw64((u64*)(mh1 + (size_t)(t & (DM - 1)) * HB) + unit * 2 + q, v);
            }
            __syncthreads();   // drain all waves' master stores
            if (tid == 0) stw32(&sync[F1 + g1], (unsigned)(t + 1));
            if (q < 2)     // h2 history after flag (off the chain)
                *(u64*)(h2buf + ((size_t)(wv * 16 + l) * T_SEQ + t) * HID + g1 * 8 + q * 4) = v;
        }
    }
}

__global__ __launch_bounds__(256) void fc_kernel(
    const bf16_t* __restrict__ h2buf, const bf16_t* __restrict__ Wfcb,
    const float* __restrict__ bfc, float* __restrict__ out)
{
    const int tid = threadIdx.x, wv = tid >> 6, lane = tid & 63;
    const int q = lane >> 4, l = lane & 15;
    const int m0 = blockIdx.x * 64 + wv * 16;
    const bf16_t* arow = h2buf + (size_t)(m0 + l) * HID + q * 8;
    const bf16_t* brow = Wfcb + (size_t)l * HID + q * 8;
    f32x4 acc[4] = {{0.f,0.f,0.f,0.f},{0.f,0.f,0.f,0.f},{0.f,0.f,0.f,0.f},{0.f,0.f,0.f,0.f}};
#pragma unroll 4
    for (int p = 0; p < 32; ++p) {
        bf16x8 av = *(const bf16x8*)(arow + p * 32);
#pragma unroll
        for (int ntile = 0; ntile < 4; ++ntile) {
            bf16x8 bv = *(const bf16x8*)(brow + (size_t)ntile * 16 * HID + p * 32);
            acc[ntile] = __builtin_amdgcn_mfma_f32_16x16x32_bf16(av, bv, acc[ntile], 0, 0, 0);
        }
    }
#pragma unroll
    for (int ntile = 0; ntile < 4; ++ntile) {
        float bv = bfc[ntile * 16 + l];
#pragma unroll
        for (int r = 0; r < 4; ++r)
            out[(size_t)(m0 + q * 4 + r) * 64 + ntile * 16 + l] = acc[ntile][r] + bv;
    }
}

extern "C" void kernel_launch(void* const* d_in, const int* in_sizes, int n_in,
                              void* d_out, int out_size, void* d_ws, size_t ws_size,
                              hipStream_t stream)
{
    const float* x    = (const float*)d_in[0];
    const float* Wih0 = (const float*)d_in[1];
    const float* Whh0 = (const float*)d_in[2];
    const float* bih0 = (const float*)d_in[3];
    const float* bhh0 = (const float*)d_in[4];
    const float* Wih1 = (const float*)d_in[5];
    const float* Whh1 = (const float*)d_in[6];
    const float* bih1 = (const float*)d_in[7];
    const float* bhh1 = (const float*)d_in[8];
    const float* Wfc  = (const float*)d_in[9];
    const float* bfc  = (const float*)d_in[10];
    float* out = (float*)d_out;

    char* ws = (char*)d_ws;
    size_t off = 0;
    auto alloc = [&](size_t bytes) -> void* {
        void* p = ws + off;
        off += (bytes + 255) & ~(size_t)255;
        return p;
    };
    bf16_t* Wf0  = (bf16_t*)alloc((size_t)64 * NF0 * 64 * 8 * 2);
    bf16_t* Wf1  = (bf16_t*)alloc((size_t)64 * NF1 * 64 * 8 * 2);
    bf16_t* WfR  = (bf16_t*)alloc((size_t)128 * NFR * 64 * 8 * 2);
    bf16_t* xswz = (bf16_t*)alloc((size_t)NB * T_SEQ * FIN * 2);
    bf16_t* h2buf= (bf16_t*)alloc((size_t)NB * T_SEQ * HID * 2);
    bf16_t* mh0  = (bf16_t*)alloc((size_t)DM * HB * 2);
    bf16_t* mh1  = (bf16_t*)alloc((size_t)DM * HB * 2);
    float*  x1r  = (float*)alloc((size_t)DX * X1SLOT * 4);
    float*  bias0= (float*)alloc(4096 * 4);
    float*  bias1= (float*)alloc(4096 * 4);
    bf16_t* Wfcb = (bf16_t*)alloc((size_t)64 * HID * 2);
    unsigned* syncp = (unsigned*)alloc(SYNC_N * 4);
    if (off > ws_size) return;

    hipFuncSetAttribute((const void*)lstm_persist,
                        hipFuncAttributeMaxDynamicSharedMemorySize, LDS_BYTES);

    prep_kernel<<<1024, 256, 0, stream>>>(x, Wih0, Whh0, bih0, bhh0,
                                          Wih1, Whh1, bih1, bhh1, Wfc,
                                          Wf0, Wf1, WfR, xswz, Wfcb,
                                          bias0, bias1, mh0, mh1, syncp);

    void* args[] = { (void*)&Wf0, (void*)&Wf1, (void*)&WfR,
                     (void*)&bias0, (void*)&bias1,
                     (void*)&xswz, (void*)&mh0, (void*)&mh1,
                     (void*)&h2buf, (void*)&x1r,
                     (void*)&syncp };
    hipLaunchCooperativeKernel((void*)lstm_persist, dim3(NBLK), dim3(512),
                               args, LDS_BYTES, stream);

    fc_kernel<<<(NB * T_SEQ) / 64, 256, 0, stream>>>(h2buf, Wfcb, bfc, out);
}